// Round 10
// baseline (78.963 us; speedup 1.0000x reference)
//
#include <hip/hip_runtime.h>
#include <hip/hip_bf16.h>

#define BB 4
#define CC 256
#define HH 64
#define WW 64
#define OO 256
#define NK2 9
#define HWP (HH*WW)      // 4096
#define KD (NK2*CC)      // 2304
#define PART_ELEMS (BB*OO*HWP)        // 4,194,304
#define XT_BYTES   8388608ull
#define WT_BYTES   1179648ull
#define PART_OFF   (XT_BYTES + WT_BYTES)

typedef __bf16 bf16x8 __attribute__((ext_vector_type(8)));
typedef float f32x4 __attribute__((ext_vector_type(4)));
typedef float f32x8 __attribute__((ext_vector_type(8)));
typedef unsigned short u16x8 __attribute__((ext_vector_type(8)));

static __device__ __forceinline__ float bf2f(unsigned short v) {
  return __uint_as_float(((unsigned)v) << 16);
}
static __device__ __forceinline__ unsigned short f2bf(float f) {
  __hip_bfloat16 h = __float2bfloat16(f);
  return __builtin_bit_cast(unsigned short, h);
}

// x [B][C][H][W] fp32  ->  xt [B][H][W][C] bf16
__global__ void k_xpose(const float* __restrict__ x, unsigned short* __restrict__ xt) {
  __shared__ float tile[32][33];
  int b  = blockIdx.z;
  int c0 = blockIdx.y * 32;
  int p0 = blockIdx.x * 32;
  int tx = threadIdx.x & 31;
  int ty = threadIdx.x >> 5;
  const float* src = x + ((size_t)b * CC + c0) * HWP + p0;
#pragma unroll
  for (int i = 0; i < 4; ++i)
    tile[ty + i * 8][tx] = src[(size_t)(ty + i * 8) * HWP + tx];
  __syncthreads();
  unsigned short* dst = xt + ((size_t)b * HWP + p0) * CC + c0;
#pragma unroll
  for (int i = 0; i < 4; ++i) {
    float v = tile[tx][ty + i * 8];
    dst[(size_t)(ty + i * 8) * CC + tx] = f2bf(v);
  }
}

// weight [O][C][3][3] fp32 -> wt2 [kpt][kk(8 of 32ch)][o][32ch-frag] bf16
__global__ void k_wt(const float* __restrict__ w, unsigned short* __restrict__ wt) {
  int i = blockIdx.x * 256 + threadIdx.x;
  if (i >= OO * KD) return;
  int kpt = i >> 16;              // /65536  (8*256*32)
  int rem = i & 65535;
  int kk = rem >> 13;             // /8192   (256*32)
  int rem2 = rem & 8191;
  int o = rem2 >> 5;
  int f = rem2 & 31;              // lg*8+j
  int c = kk * 32 + f;
  wt[i] = f2bf(w[((size_t)o * CC + c) * NK2 + kpt]);
}

// Mt=256 (4 image rows), all 9 kpt per block, CHN=64 channel-quarter.
// 1024 thr / 16 waves as 4(o) x 4(m); wave tile o64 x m64; acc[4][4].
// Grid = 64 tiles x 4 kh = 256 blocks = 1/CU. Panel [256px][64ch] = 32KB LDS.
__launch_bounds__(1024, 1)
__global__ void k_dcn2(const unsigned short* __restrict__ xt,
                       const unsigned short* __restrict__ wt,
                       const float* __restrict__ sp,
                       unsigned short* __restrict__ parts) {
  __shared__ __align__(16) unsigned short Alds[256 * 64];   // 32 KB

  const int tid = threadIdx.x;
  // XCD-chunked swizzle over 256 blocks
  const int bid = blockIdx.x;
  const int swz = (bid & 7) * 32 + (bid >> 3);
  const int kh = swz & 3;                   // channel quarter
  const int tile = swz >> 2;                // 0..63
  const int y0 = (tile & 15) * 4;
  const int b = tile >> 4;

  // gather mapping: 8 lanes per corner (128B), group owns 2 pixels
  const int t8 = tid & 7;
  const int grp = tid >> 3;                 // 0..127

  // mfma mapping: 16 waves as (wo, wm)
  const int wv = tid >> 6;
  const int wo = wv & 3;
  const int wm = wv >> 2;
  const int lane = tid & 63;
  const int l15 = lane & 15;
  const int lg = lane >> 4;

  f32x4 acc[4][4];
#pragma unroll
  for (int i = 0; i < 4; ++i)
#pragma unroll
    for (int j = 0; j < 4; ++j)
      acc[i][j] = (f32x4){0.f, 0.f, 0.f, 0.f};

  char* Ab = (char*)Alds;
  const unsigned short* xb = xt + (size_t)b * HWP * CC + kh * 64;
  const float* spb = sp + (size_t)b * 18 * HWP;

  for (int kpt = 0; kpt < NK2; ++kpt) {
    // ---- build sampled panel [256 px][64 ch] ----
#pragma unroll
    for (int pi = 0; pi < 2; ++pi) {
      const int pp = grp + pi * 128;        // panel row
      const int yim = y0 + (pp >> 6);
      const int xim = pp & 63;
      float offY = spb[(2 * kpt) * HWP + yim * WW + xim];
      float offX = spb[(2 * kpt + 1) * HWP + yim * WW + xim];
      float py = (float)yim + offY;
      float px = (float)xim + offX;
      float fy = floorf(py), fx = floorf(px);
      float ly = py - fy, lx = px - fx;
      int y0i = (int)fy, x0i = (int)fx;
      int y1i = y0i + 1, x1i = x0i + 1;
      bool vy0 = (y0i >= 0) & (y0i < HH);
      bool vy1 = (y1i >= 0) & (y1i < HH);
      bool vx0 = (x0i >= 0) & (x0i < WW);
      bool vx1 = (x1i >= 0) & (x1i < WW);
      float w00 = (1.f - ly) * (1.f - lx);
      float w01 = (1.f - ly) * lx;
      float w10 = ly * (1.f - lx);
      float w11 = ly * lx;
      w00 = (vy0 && vx0) ? w00 : 0.f;
      w01 = (vy0 && vx1) ? w01 : 0.f;
      w10 = (vy1 && vx0) ? w10 : 0.f;
      w11 = (vy1 && vx1) ? w11 : 0.f;
      int yc0 = min(max(y0i, 0), HH - 1), yc1 = min(max(y1i, 0), HH - 1);
      int xc0 = min(max(x0i, 0), WW - 1), xc1 = min(max(x1i, 0), WW - 1);
      const unsigned short* q = xb + t8 * 8;
      u16x8 a00 = *reinterpret_cast<const u16x8*>(q + (yc0 * WW + xc0) * CC);
      u16x8 a01 = *reinterpret_cast<const u16x8*>(q + (yc0 * WW + xc1) * CC);
      u16x8 a10 = *reinterpret_cast<const u16x8*>(q + (yc1 * WW + xc0) * CC);
      u16x8 a11 = *reinterpret_cast<const u16x8*>(q + (yc1 * WW + xc1) * CC);
      u16x8 r;
#pragma unroll
      for (int j = 0; j < 8; ++j) {
        float s = fmaf(w11, bf2f(a11[j]),
                  fmaf(w10, bf2f(a10[j]),
                  fmaf(w01, bf2f(a01[j]), w00 * bf2f(a00[j]))));
        r[j] = f2bf(s);
      }
      unsigned bo = (unsigned)(pp * 128 + t8 * 16) ^ (unsigned)((pp & 7) << 4);
      *reinterpret_cast<u16x8*>(Ab + bo) = r;
    }
    __syncthreads();

    // ---- MFMA: K = 64 (2 chunks of 32) ----
#pragma unroll
    for (int kk = 0; kk < 2; ++kk) {
      bf16x8 afr[4], bfr[4];
#pragma unroll
      for (int fm = 0; fm < 4; ++fm)
        afr[fm] = __builtin_bit_cast(bf16x8, *reinterpret_cast<const u16x8*>(
            wt + (size_t)(kpt * 8 + kh * 2 + kk) * 8192
               + (wo * 64 + fm * 16 + l15) * 32 + lg * 8));
#pragma unroll
      for (int fn = 0; fn < 4; ++fn) {
        int mr = wm * 64 + fn * 16 + l15;
        unsigned bo = (unsigned)(mr * 128 + kk * 64 + lg * 16) ^ (unsigned)((mr & 7) << 4);
        bfr[fn] = __builtin_bit_cast(bf16x8, *reinterpret_cast<const u16x8*>(Ab + bo));
      }
#pragma unroll
      for (int fm = 0; fm < 4; ++fm)
#pragma unroll
        for (int fn = 0; fn < 4; ++fn)
          acc[fm][fn] = __builtin_amdgcn_mfma_f32_16x16x32_bf16(afr[fm], bfr[fn], acc[fm][fn], 0, 0, 0);
    }
    __syncthreads();
  }

  // ---- epilogue: bf16 partial for this channel-quarter ----
  unsigned short* dp = parts + (size_t)kh * PART_ELEMS;
#pragma unroll
  for (int fm = 0; fm < 4; ++fm) {
#pragma unroll
    for (int fn = 0; fn < 4; ++fn) {
#pragma unroll
      for (int r = 0; r < 4; ++r) {
        int o = wo * 64 + fm * 16 + lg * 4 + r;
        int m = wm * 64 + fn * 16 + l15;
        int yy = y0 + (m >> 6);
        int xx = m & 63;
        dp[(((size_t)b * OO + o) * HH + yy) * WW + xx] = f2bf(acc[fm][fn][r]);
      }
    }
  }
}

// ---------------- fallback (small ws): R9 path, single pass ----------------
template<int KPTN, int NG, int CHN, int BF16OUT>
__launch_bounds__(512)
__global__ void k_dcn(const unsigned short* __restrict__ xt,
                      const unsigned short* __restrict__ wt,
                      const float* __restrict__ sp,
                      void* __restrict__ dstv) {
  constexpr int NKH = 256 / CHN;
  constexpr int RS = CHN * 2;
  constexpr int NCG = CHN / 64;
  constexpr int NKK = CHN / 32;
  __shared__ __align__(16) unsigned short Alds[128 * CHN];

  const int tid = threadIdx.x;
  constexpr int NBLK = NG * NKH * BB * (HH / 2);
  const int hw = blockIdx.x;
  const int swz = (hw & 7) * (NBLK / 8) + (hw >> 3);
  const int gg = swz % (NG * NKH);
  const int gk = gg / NKH;
  const int kh = gg % NKH;
  const int rest = swz / (NG * NKH);
  const int y0 = (rest & 31) * 2;
  const int b = rest >> 5;
  const int kpt0 = gk * KPTN;
  const int cb = kh * CHN;

  const int t8 = tid & 7;
  const int pxb = tid >> 3;

  const int wv = tid >> 6;
  const int lane = tid & 63;
  const int l15 = lane & 15;
  const int lg = lane >> 4;
  const int obase = wv * 32;

  f32x4 acc[2][8];
#pragma unroll
  for (int i = 0; i < 2; ++i)
#pragma unroll
    for (int j = 0; j < 8; ++j)
      acc[i][j] = (f32x4){0.f, 0.f, 0.f, 0.f};

  const unsigned short* wbase[2];
#pragma unroll
  for (int fm = 0; fm < 2; ++fm)
    wbase[fm] = wt + (size_t)(obase + fm * 16 + l15) * 32 + lg * 8;

  char* Ab = (char*)Alds;
  const unsigned short* xb = xt + (size_t)b * HWP * CC + cb;

  for (int t = 0; t < KPTN; ++t) {
    const int kpt = kpt0 + t;
#pragma unroll
    for (int h = 0; h < 2; ++h) {
      const int pm = h * 64 + pxb;
      float offY = sp[((size_t)b * 18 + 2 * kpt) * HWP + (y0 + h) * WW + pxb];
      float offX = sp[((size_t)b * 18 + 2 * kpt + 1) * HWP + (y0 + h) * WW + pxb];
      float py = (float)(y0 + h) + offY;
      float pxx = (float)pxb + offX;
      float fy = floorf(py), fx = floorf(pxx);
      float ly = py - fy, lx = pxx - fx;
      int y0i = (int)fy, x0i = (int)fx;
      int y1i = y0i + 1, x1i = x0i + 1;
      bool vy0 = (y0i >= 0) & (y0i < HH);
      bool vy1 = (y1i >= 0) & (y1i < HH);
      bool vx0 = (x0i >= 0) & (x0i < WW);
      bool vx1 = (x1i >= 0) & (x1i < WW);
      float w00 = (1.f - ly) * (1.f - lx);
      float w01 = (1.f - ly) * lx;
      float w10 = ly * (1.f - lx);
      float w11 = ly * lx;
      w00 = (vy0 && vx0) ? w00 : 0.f;
      w01 = (vy0 && vx1) ? w01 : 0.f;
      w10 = (vy1 && vx0) ? w10 : 0.f;
      w11 = (vy1 && vx1) ? w11 : 0.f;
      int yc0 = min(max(y0i, 0), HH - 1), yc1 = min(max(y1i, 0), HH - 1);
      int xc0 = min(max(x0i, 0), WW - 1), xc1 = min(max(x1i, 0), WW - 1);
      const unsigned short* p00 = xb + (yc0 * WW + xc0) * CC + t8 * 8;
      const unsigned short* p01 = xb + (yc0 * WW + xc1) * CC + t8 * 8;
      const unsigned short* p10 = xb + (yc1 * WW + xc0) * CC + t8 * 8;
      const unsigned short* p11 = xb + (yc1 * WW + xc1) * CC + t8 * 8;
#pragma unroll
      for (int cg = 0; cg < NCG; ++cg) {
        u16x8 a00 = *reinterpret_cast<const u16x8*>(p00 + cg * 64);
        u16x8 a01 = *reinterpret_cast<const u16x8*>(p01 + cg * 64);
        u16x8 a10 = *reinterpret_cast<const u16x8*>(p10 + cg * 64);
        u16x8 a11 = *reinterpret_cast<const u16x8*>(p11 + cg * 64);
        u16x8 r;
#pragma unroll
        for (int j = 0; j < 8; ++j) {
          float s = fmaf(w11, bf2f(a11[j]),
                    fmaf(w10, bf2f(a10[j]),
                    fmaf(w01, bf2f(a01[j]), w00 * bf2f(a00[j]))));
          r[j] = f2bf(s);
        }
        unsigned bo = (unsigned)(pm * RS + cg * 128 + t8 * 16) ^ (unsigned)((pm & 7) << 4);
        *reinterpret_cast<u16x8*>(Ab + bo) = r;
      }
    }
    __syncthreads();

#pragma unroll
    for (int kk = 0; kk < NKK; ++kk) {
      bf16x8 afr[2], bfr[8];
#pragma unroll
      for (int fm = 0; fm < 2; ++fm)
        afr[fm] = __builtin_bit_cast(bf16x8,
            *reinterpret_cast<const u16x8*>(wbase[fm] + (size_t)(kpt * 8 + kh * NKK + kk) * 8192));
#pragma unroll
      for (int fn = 0; fn < 8; ++fn) {
        int mr = fn * 16 + l15;
        unsigned bo = (unsigned)(mr * RS + kk * 64 + lg * 16) ^ (unsigned)((mr & 7) << 4);
        bfr[fn] = __builtin_bit_cast(bf16x8, *reinterpret_cast<const u16x8*>(Ab + bo));
      }
#pragma unroll
      for (int fm = 0; fm < 2; ++fm)
#pragma unroll
        for (int fn = 0; fn < 8; ++fn)
          acc[fm][fn] = __builtin_amdgcn_mfma_f32_16x16x32_bf16(afr[fm], bfr[fn], acc[fm][fn], 0, 0, 0);
    }
    __syncthreads();
  }

#pragma unroll
  for (int fm = 0; fm < 2; ++fm) {
#pragma unroll
    for (int fn = 0; fn < 8; ++fn) {
#pragma unroll
      for (int r = 0; r < 4; ++r) {
        int o = obase + fm * 16 + lg * 4 + r;
        int m = fn * 16 + l15;
        int yy = y0 + (m >> 6);
        int xx = m & 63;
        size_t idx = (((size_t)b * OO + o) * HH + yy) * WW + xx;
        float v = acc[fm][fn][r];
        if (BF16OUT) {
          ((unsigned short*)dstv)[(size_t)gg * PART_ELEMS + idx] = f2bf(v);
        } else {
          ((float*)dstv)[idx] = fmaxf(v, 0.0f);
        }
      }
    }
  }
}

// out = relu(sum of NP bf16 partials), 8 elems/thread
template<int NP>
__global__ void k_reduceN(const unsigned short* __restrict__ parts, float* __restrict__ out, int n8) {
  int i = blockIdx.x * 256 + threadIdx.x;
  if (i >= n8) return;
  const u16x8* p = (const u16x8*)parts;
  f32x8 s;
#pragma unroll
  for (int j = 0; j < 8; ++j) s[j] = 0.0f;
#pragma unroll
  for (int q = 0; q < NP; ++q) {
    u16x8 v = p[i + (size_t)q * (PART_ELEMS / 8)];
#pragma unroll
    for (int j = 0; j < 8; ++j) s[j] += bf2f(v[j]);
  }
  f32x8 o;
#pragma unroll
  for (int j = 0; j < 8; ++j) o[j] = fmaxf(s[j], 0.0f);
  *reinterpret_cast<f32x8*>(out + (size_t)i * 8) = o;
}

extern "C" void kernel_launch(void* const* d_in, const int* in_sizes, int n_in,
                              void* d_out, int out_size, void* d_ws, size_t ws_size,
                              hipStream_t stream) {
  const float* x = (const float*)d_in[0];
  const float* sp = (const float*)d_in[1];
  const float* w = (const float*)d_in[2];
  float* out = (float*)d_out;

  unsigned short* xt = (unsigned short*)d_ws;
  unsigned short* wt = (unsigned short*)((char*)d_ws + XT_BYTES);
  unsigned short* parts = (unsigned short*)((char*)d_ws + PART_OFF);

  k_xpose<<<dim3(HWP / 32, CC / 32, BB), 256, 0, stream>>>(x, xt);
  k_wt<<<(OO * KD + 255) / 256, 256, 0, stream>>>(w, wt);

  const size_t need = PART_OFF + 4ull * PART_ELEMS * sizeof(unsigned short);
  if (ws_size >= need) {
    k_dcn2<<<256, 1024, 0, stream>>>(xt, wt, sp, parts);
    k_reduceN<4><<<PART_ELEMS / 8 / 256, 256, 0, stream>>>(parts, out, PART_ELEMS / 8);
  } else {
    k_dcn<9, 1, 256, 0><<<BB * (HH / 2), 512, 0, stream>>>(xt, wt, sp, out);
  }
}

// Round 11
// 60.208 us; speedup vs baseline: 1.3115x; 1.3115x over previous
//
#include <hip/hip_runtime.h>
#include <hip/hip_bf16.h>

#define BB 4
#define CC 256
#define HH 64
#define WW 64
#define OO 256
#define NK2 9
#define HWP (HH*WW)      // 4096
#define KD (NK2*CC)      // 2304
#define PART_ELEMS (BB*OO*HWP)        // 4,194,304
#define XT_BYTES   8388608ull
#define WT_BYTES   1179648ull
#define PART_OFF   (XT_BYTES + WT_BYTES)

typedef __bf16 bf16x8 __attribute__((ext_vector_type(8)));
typedef float f32x4 __attribute__((ext_vector_type(4)));
typedef float f32x8 __attribute__((ext_vector_type(8)));
typedef unsigned short u16x8 __attribute__((ext_vector_type(8)));

static __device__ __forceinline__ float bf2f(unsigned short v) {
  return __uint_as_float(((unsigned)v) << 16);
}
static __device__ __forceinline__ unsigned short f2bf(float f) {
  __hip_bfloat16 h = __float2bfloat16(f);
  return __builtin_bit_cast(unsigned short, h);
}

// x [B][C][H][W] fp32  ->  xt [B][H][W][C] bf16
__global__ void k_xpose(const float* __restrict__ x, unsigned short* __restrict__ xt) {
  __shared__ float tile[32][33];
  int b  = blockIdx.z;
  int c0 = blockIdx.y * 32;
  int p0 = blockIdx.x * 32;
  int tx = threadIdx.x & 31;
  int ty = threadIdx.x >> 5;
  const float* src = x + ((size_t)b * CC + c0) * HWP + p0;
#pragma unroll
  for (int i = 0; i < 4; ++i)
    tile[ty + i * 8][tx] = src[(size_t)(ty + i * 8) * HWP + tx];
  __syncthreads();
  unsigned short* dst = xt + ((size_t)b * HWP + p0) * CC + c0;
#pragma unroll
  for (int i = 0; i < 4; ++i) {
    float v = tile[tx][ty + i * 8];
    dst[(size_t)(ty + i * 8) * CC + tx] = f2bf(v);
  }
}

// weight [O][C][3][3] fp32 -> wt2 [kpt][kkg(8 of 32ch)][o][32ch-frag] bf16
__global__ void k_wt(const float* __restrict__ w, unsigned short* __restrict__ wt) {
  int i = blockIdx.x * 256 + threadIdx.x;
  if (i >= OO * KD) return;
  int kpt = i >> 16;              // /65536  (8*256*32)
  int rem = i & 65535;
  int kk = rem >> 13;             // /8192   (256*32)
  int rem2 = rem & 8191;
  int o = rem2 >> 5;
  int f = rem2 & 31;              // lg*8+j
  int c = kk * 32 + f;
  wt[i] = f2bf(w[((size_t)o * CC + c) * NK2 + kpt]);
}

// Pipelined implicit GEMM. Mt=128 (2 image rows), 512 thr / 8 waves,
// wave tile o32 x m128, acc[2][8]. 6 K-stages per block (3 kpt x 2 ch-halves
// of 128ch), NG=3 kpt-groups -> 3 bf16 partials. Panel 32KB double-buffered.
// Per stage: barrier -> MFMA(s) [h0(s+1) gathers in flight] -> blend h0 ->
// issue h1 -> blend h1 -> issue h0(s+2). One barrier per stage.
__launch_bounds__(512)
__global__ void k_dcn_p(const unsigned short* __restrict__ xt,
                        const unsigned short* __restrict__ wt,
                        const float* __restrict__ sp,
                        unsigned short* __restrict__ parts) {
  __shared__ __align__(16) unsigned short Alds[2][128 * 128];   // 2 x 32KB

  const int tid = threadIdx.x;
  const int hw = blockIdx.x;
  const int swz = (hw & 7) * 48 + (hw >> 3);   // NBLK=384, XCD-chunked
  const int g = swz % 3;                       // kpt group
  const int rest = swz / 3;
  const int y0 = (rest & 31) * 2;
  const int b = rest >> 5;
  const int kpt0 = g * 3;

  // gather mapping: 8 lanes cover 128B; pxb = pixel x; h selects image row
  const int t8 = tid & 7;
  const int pxb = tid >> 3;                    // 0..63

  // mfma mapping: 8 waves x (o32 x m128)
  const int wv = tid >> 6;
  const int lane = tid & 63;
  const int l15 = lane & 15;
  const int lg = lane >> 4;
  const int obase = wv * 32;

  float offY[2][3], offX[2][3];
#pragma unroll
  for (int h = 0; h < 2; ++h)
#pragma unroll
    for (int t = 0; t < 3; ++t) {
      offY[h][t] = sp[((size_t)b * 18 + 2 * (kpt0 + t)) * HWP + (y0 + h) * WW + pxb];
      offX[h][t] = sp[((size_t)b * 18 + 2 * (kpt0 + t) + 1) * HWP + (y0 + h) * WW + pxb];
    }

  f32x4 acc[2][8];
#pragma unroll
  for (int i = 0; i < 2; ++i)
#pragma unroll
    for (int j = 0; j < 8; ++j)
      acc[i][j] = (f32x4){0.f, 0.f, 0.f, 0.f};

  const unsigned short* xb = xt + (size_t)b * HWP * CC;

  float w00, w01, w10, w11;
  unsigned c00, c01, c10, c11;                 // corner element offsets
  u16x8 d0, d1, d2, d3, d4, d5, d6, d7;

// compute weights + corner offsets for (pixel row H, kpt index T)
#define CALC(H, T)                                                             \
  {                                                                            \
    float py = (float)(y0 + (H)) + offY[H][T];                                 \
    float px = (float)pxb + offX[H][T];                                        \
    float fy = floorf(py), fx = floorf(px);                                    \
    float ly = py - fy, lx = px - fx;                                          \
    int y0i = (int)fy, x0i = (int)fx;                                          \
    int y1i = y0i + 1, x1i = x0i + 1;                                          \
    bool vy0 = (y0i >= 0) & (y0i < HH);                                        \
    bool vy1 = (y1i >= 0) & (y1i < HH);                                        \
    bool vx0 = (x0i >= 0) & (x0i < WW);                                        \
    bool vx1 = (x1i >= 0) & (x1i < WW);                                        \
    w00 = (1.f - ly) * (1.f - lx);                                             \
    w01 = (1.f - ly) * lx;                                                     \
    w10 = ly * (1.f - lx);                                                     \
    w11 = ly * lx;                                                             \
    w00 = (vy0 && vx0) ? w00 : 0.f;                                            \
    w01 = (vy0 && vx1) ? w01 : 0.f;                                            \
    w10 = (vy1 && vx0) ? w10 : 0.f;                                            \
    w11 = (vy1 && vx1) ? w11 : 0.f;                                            \
    int yc0 = min(max(y0i, 0), HH - 1), yc1 = min(max(y1i, 0), HH - 1);        \
    int xc0 = min(max(x0i, 0), WW - 1), xc1 = min(max(x1i, 0), WW - 1);        \
    c00 = (unsigned)((yc0 * WW + xc0) * CC);                                   \
    c01 = (unsigned)((yc0 * WW + xc1) * CC);                                   \
    c10 = (unsigned)((yc1 * WW + xc0) * CC);                                   \
    c11 = (unsigned)((yc1 * WW + xc1) * CC);                                   \
  }

// issue 8 gather loads (4 corners x 2 x 128B) for stage S (ch-half = S&1)
#define ISSUE(S)                                                               \
  {                                                                            \
    const unsigned short* q = xb + ((S) & 1) * 128 + t8 * 8;                   \
    d0 = *reinterpret_cast<const u16x8*>(q + c00);                             \
    d1 = *reinterpret_cast<const u16x8*>(q + c00 + 64);                        \
    d2 = *reinterpret_cast<const u16x8*>(q + c01);                             \
    d3 = *reinterpret_cast<const u16x8*>(q + c01 + 64);                        \
    d4 = *reinterpret_cast<const u16x8*>(q + c10);                             \
    d5 = *reinterpret_cast<const u16x8*>(q + c10 + 64);                        \
    d6 = *reinterpret_cast<const u16x8*>(q + c11);                             \
    d7 = *reinterpret_cast<const u16x8*>(q + c11 + 64);                        \
  }

// blend pending loads, write panel rows for (stage S, pixel row H)
#define BLEND(S, H)                                                            \
  {                                                                            \
    char* Bp = (char*)Alds[(S) & 1];                                           \
    const int pm = (H) * 64 + pxb;                                             \
    u16x8 r0, r1;                                                              \
    _Pragma("unroll")                                                          \
    for (int j = 0; j < 8; ++j) {                                              \
      float s0 = fmaf(w11, bf2f(d6[j]), fmaf(w10, bf2f(d4[j]),                 \
                 fmaf(w01, bf2f(d2[j]), w00 * bf2f(d0[j]))));                  \
      float s1 = fmaf(w11, bf2f(d7[j]), fmaf(w10, bf2f(d5[j]),                 \
                 fmaf(w01, bf2f(d3[j]), w00 * bf2f(d1[j]))));                  \
      r0[j] = f2bf(s0);                                                        \
      r1[j] = f2bf(s1);                                                        \
    }                                                                          \
    unsigned bo0 = (unsigned)(pm * 256 + t8 * 16) ^ (unsigned)((pm & 7) << 4); \
    unsigned bo1 = (unsigned)(pm * 256 + 128 + t8 * 16) ^ (unsigned)((pm & 7) << 4); \
    *reinterpret_cast<u16x8*>(Bp + bo0) = r0;                                  \
    *reinterpret_cast<u16x8*>(Bp + bo1) = r1;                                  \
  }

// MFMA over stage S (kpt index T): K = 128 = 4 chunks of 32
#define MFMA_S(S, T)                                                           \
  {                                                                            \
    const char* Bp = (const char*)Alds[(S) & 1];                               \
    _Pragma("unroll")                                                          \
    for (int kk = 0; kk < 4; ++kk) {                                           \
      bf16x8 afr[2], bfr[8];                                                   \
      _Pragma("unroll")                                                        \
      for (int fm = 0; fm < 2; ++fm)                                           \
        afr[fm] = __builtin_bit_cast(bf16x8, *reinterpret_cast<const u16x8*>(  \
            wt + (size_t)((kpt0 + (T)) * 8 + ((S) & 1) * 4 + kk) * 8192        \
               + (obase + fm * 16 + l15) * 32 + lg * 8));                      \
      _Pragma("unroll")                                                        \
      for (int fn = 0; fn < 8; ++fn) {                                         \
        int mr = fn * 16 + l15;                                                \
        unsigned bo = (unsigned)(mr * 256 + kk * 64 + lg * 16) ^ (unsigned)((mr & 7) << 4); \
        bfr[fn] = __builtin_bit_cast(bf16x8, *reinterpret_cast<const u16x8*>(Bp + bo)); \
      }                                                                        \
      _Pragma("unroll")                                                        \
      for (int fm = 0; fm < 2; ++fm)                                           \
        _Pragma("unroll")                                                      \
        for (int fn = 0; fn < 8; ++fn)                                         \
          acc[fm][fn] = __builtin_amdgcn_mfma_f32_16x16x32_bf16(afr[fm], bfr[fn], acc[fm][fn], 0, 0, 0); \
    }                                                                          \
  }

  // ---- prologue: fill stage 0, start stage 1 h0 ----
  CALC(0, 0); ISSUE(0); BLEND(0, 0);
  CALC(1, 0); ISSUE(0); BLEND(0, 1);
  CALC(0, 0); ISSUE(1);
  __syncthreads();

  // ---- steady pipeline: stages 0..5 = (kpt 0..2) x (ch-half 0..1) ----
  MFMA_S(0, 0);
  BLEND(1, 0);
  CALC(1, 0); ISSUE(1); BLEND(1, 1);
  CALC(0, 1); ISSUE(2);
  __syncthreads();

  MFMA_S(1, 0);
  BLEND(2, 0);
  CALC(1, 1); ISSUE(2); BLEND(2, 1);
  CALC(0, 1); ISSUE(3);
  __syncthreads();

  MFMA_S(2, 1);
  BLEND(3, 0);
  CALC(1, 1); ISSUE(3); BLEND(3, 1);
  CALC(0, 2); ISSUE(4);
  __syncthreads();

  MFMA_S(3, 1);
  BLEND(4, 0);
  CALC(1, 2); ISSUE(4); BLEND(4, 1);
  CALC(0, 2); ISSUE(5);
  __syncthreads();

  MFMA_S(4, 2);
  BLEND(5, 0);
  CALC(1, 2); ISSUE(5); BLEND(5, 1);
  __syncthreads();

  MFMA_S(5, 2);

  // ---- epilogue: bf16 partial for this kpt-group ----
  unsigned short* dp = parts + (size_t)g * PART_ELEMS;
#pragma unroll
  for (int fm = 0; fm < 2; ++fm) {
#pragma unroll
    for (int fn = 0; fn < 8; ++fn) {
#pragma unroll
      for (int r = 0; r < 4; ++r) {
        int o = obase + fm * 16 + lg * 4 + r;
        int m = fn * 16 + l15;
        int yy = y0 + (m >> 6);
        int xx = m & 63;
        dp[(((size_t)b * OO + o) * HH + yy) * WW + xx] = f2bf(acc[fm][fn][r]);
      }
    }
  }
}

// ---------------- fallback (small ws): single-pass, f32 out ----------------
__launch_bounds__(512)
__global__ void k_dcn_f(const unsigned short* __restrict__ xt,
                        const unsigned short* __restrict__ wt,
                        const float* __restrict__ sp,
                        float* __restrict__ outp) {
  __shared__ __align__(16) unsigned short Alds[128 * 256];

  const int tid = threadIdx.x;
  const int hw = blockIdx.x;
  const int swz = (hw & 7) * 16 + (hw >> 3);   // NBLK=128
  const int y0 = (swz & 31) * 2;
  const int b = swz >> 5;

  const int t8 = tid & 7;
  const int pxb = tid >> 3;

  const int wv = tid >> 6;
  const int lane = tid & 63;
  const int l15 = lane & 15;
  const int lg = lane >> 4;
  const int obase = wv * 32;

  f32x4 acc[2][8];
#pragma unroll
  for (int i = 0; i < 2; ++i)
#pragma unroll
    for (int j = 0; j < 8; ++j)
      acc[i][j] = (f32x4){0.f, 0.f, 0.f, 0.f};

  char* Ab = (char*)Alds;
  const unsigned short* xb = xt + (size_t)b * HWP * CC;

  for (int kpt = 0; kpt < NK2; ++kpt) {
#pragma unroll
    for (int h = 0; h < 2; ++h) {
      const int pm = h * 64 + pxb;
      float offY = sp[((size_t)b * 18 + 2 * kpt) * HWP + (y0 + h) * WW + pxb];
      float offX = sp[((size_t)b * 18 + 2 * kpt + 1) * HWP + (y0 + h) * WW + pxb];
      float py = (float)(y0 + h) + offY;
      float pxx = (float)pxb + offX;
      float fy = floorf(py), fx = floorf(pxx);
      float ly = py - fy, lx = pxx - fx;
      int y0i = (int)fy, x0i = (int)fx;
      int y1i = y0i + 1, x1i = x0i + 1;
      bool vy0 = (y0i >= 0) & (y0i < HH);
      bool vy1 = (y1i >= 0) & (y1i < HH);
      bool vx0 = (x0i >= 0) & (x0i < WW);
      bool vx1 = (x1i >= 0) & (x1i < WW);
      float w00 = (1.f - ly) * (1.f - lx);
      float w01 = (1.f - ly) * lx;
      float w10 = ly * (1.f - lx);
      float w11 = ly * lx;
      w00 = (vy0 && vx0) ? w00 : 0.f;
      w01 = (vy0 && vx1) ? w01 : 0.f;
      w10 = (vy1 && vx0) ? w10 : 0.f;
      w11 = (vy1 && vx1) ? w11 : 0.f;
      int yc0 = min(max(y0i, 0), HH - 1), yc1 = min(max(y1i, 0), HH - 1);
      int xc0 = min(max(x0i, 0), WW - 1), xc1 = min(max(x1i, 0), WW - 1);
      const unsigned short* p00 = xb + (yc0 * WW + xc0) * CC + t8 * 8;
      const unsigned short* p01 = xb + (yc0 * WW + xc1) * CC + t8 * 8;
      const unsigned short* p10 = xb + (yc1 * WW + xc0) * CC + t8 * 8;
      const unsigned short* p11 = xb + (yc1 * WW + xc1) * CC + t8 * 8;
#pragma unroll
      for (int cg = 0; cg < 4; ++cg) {
        u16x8 a00 = *reinterpret_cast<const u16x8*>(p00 + cg * 64);
        u16x8 a01 = *reinterpret_cast<const u16x8*>(p01 + cg * 64);
        u16x8 a10 = *reinterpret_cast<const u16x8*>(p10 + cg * 64);
        u16x8 a11 = *reinterpret_cast<const u16x8*>(p11 + cg * 64);
        u16x8 r;
#pragma unroll
        for (int j = 0; j < 8; ++j) {
          float s = fmaf(w11, bf2f(a11[j]),
                    fmaf(w10, bf2f(a10[j]),
                    fmaf(w01, bf2f(a01[j]), w00 * bf2f(a00[j]))));
          r[j] = f2bf(s);
        }
        unsigned bo = (unsigned)(pm * 512 + cg * 128 + t8 * 16) ^ (unsigned)((pm & 7) << 4);
        *reinterpret_cast<u16x8*>(Ab + bo) = r;
      }
    }
    __syncthreads();

#pragma unroll
    for (int kk = 0; kk < 8; ++kk) {
      bf16x8 afr[2], bfr[8];
#pragma unroll
      for (int fm = 0; fm < 2; ++fm)
        afr[fm] = __builtin_bit_cast(bf16x8, *reinterpret_cast<const u16x8*>(
            wt + (size_t)(kpt * 8 + kk) * 8192 + (obase + fm * 16 + l15) * 32 + lg * 8));
#pragma unroll
      for (int fn = 0; fn < 8; ++fn) {
        int mr = fn * 16 + l15;
        unsigned bo = (unsigned)(mr * 512 + kk * 64 + lg * 16) ^ (unsigned)((mr & 7) << 4);
        bfr[fn] = __builtin_bit_cast(bf16x8, *reinterpret_cast<const u16x8*>(Ab + bo));
      }
#pragma unroll
      for (int fm = 0; fm < 2; ++fm)
#pragma unroll
        for (int fn = 0; fn < 8; ++fn)
          acc[fm][fn] = __builtin_amdgcn_mfma_f32_16x16x32_bf16(afr[fm], bfr[fn], acc[fm][fn], 0, 0, 0);
    }
    __syncthreads();
  }

#pragma unroll
  for (int fm = 0; fm < 2; ++fm) {
#pragma unroll
    for (int fn = 0; fn < 8; ++fn) {
#pragma unroll
      for (int r = 0; r < 4; ++r) {
        int o = obase + fm * 16 + lg * 4 + r;
        int m = fn * 16 + l15;
        int yy = y0 + (m >> 6);
        int xx = m & 63;
        outp[(((size_t)b * OO + o) * HH + yy) * WW + xx] = fmaxf(acc[fm][fn][r], 0.0f);
      }
    }
  }
}

// out = relu(sum of NP bf16 partials), 8 elems/thread
template<int NP>
__global__ void k_reduceN(const unsigned short* __restrict__ parts, float* __restrict__ out, int n8) {
  int i = blockIdx.x * 256 + threadIdx.x;
  if (i >= n8) return;
  const u16x8* p = (const u16x8*)parts;
  f32x8 s;
#pragma unroll
  for (int j = 0; j < 8; ++j) s[j] = 0.0f;
#pragma unroll
  for (int q = 0; q < NP; ++q) {
    u16x8 v = p[i + (size_t)q * (PART_ELEMS / 8)];
#pragma unroll
    for (int j = 0; j < 8; ++j) s[j] += bf2f(v[j]);
  }
  f32x8 o;
#pragma unroll
  for (int j = 0; j < 8; ++j) o[j] = fmaxf(s[j], 0.0f);
  *reinterpret_cast<f32x8*>(out + (size_t)i * 8) = o;
}

extern "C" void kernel_launch(void* const* d_in, const int* in_sizes, int n_in,
                              void* d_out, int out_size, void* d_ws, size_t ws_size,
                              hipStream_t stream) {
  const float* x = (const float*)d_in[0];
  const float* sp = (const float*)d_in[1];
  const float* w = (const float*)d_in[2];
  float* out = (float*)d_out;

  unsigned short* xt = (unsigned short*)d_ws;
  unsigned short* wt = (unsigned short*)((char*)d_ws + XT_BYTES);
  unsigned short* parts = (unsigned short*)((char*)d_ws + PART_OFF);

  k_xpose<<<dim3(HWP / 32, CC / 32, BB), 256, 0, stream>>>(x, xt);
  k_wt<<<(OO * KD + 255) / 256, 256, 0, stream>>>(w, wt);

  const size_t need = PART_OFF + 3ull * PART_ELEMS * sizeof(unsigned short);
  if (ws_size >= need) {
    k_dcn_p<<<384, 512, 0, stream>>>(xt, wt, sp, parts);
    k_reduceN<3><<<PART_ELEMS / 8 / 256, 256, 0, stream>>>(parts, out, PART_ELEMS / 8);
  } else {
    k_dcn_f<<<128, 512, 0, stream>>>(xt, wt, sp, out);
  }
}